// Round 9
// baseline (166.246 us; speedup 1.0000x reference)
//
#include <hip/hip_runtime.h>
#include <hip/hip_bf16.h>

// EdgeBlock: out[e] = relu(concat(edge[e], node[recv[e]], node[send[e]], g) @ W1 + b1) @ W2 + b2
// Round 9: wave-pair autonomous tiles.
//  - block = 128 threads (2 waves); tile = 16 edges; wave v owns hidden cols [v*64,v*64+64)
//    (W1 frags pinned, 96 VGPR) and out cols [v*32,v*32+32) (W2 frags pinned, 32 VGPR)
//  - both waves gather the same 16 edges straight into registers (A never in LDS);
//    only h crosses waves: 4KB double-buffered frag-order h -> ONE barrier per tile
//  - edge loads permuted to 1 cache line per instruction (k-map baked into W1F f<2)
//  - T14 1-deep gather prefetch + 2-deep idx prefetch, lgkm-only barrier

typedef __bf16 bf16x8 __attribute__((ext_vector_type(8)));
typedef __bf16 bf16x2 __attribute__((ext_vector_type(2)));
typedef float f32x4 __attribute__((ext_vector_type(4)));

#define GRID_MAIN 4096
#define SWZ(x) ((x) ^ (((x) >> 3) & 7))
// ws layout:
//   [0, 49152)       W1F bf16 frag-order; f<2 (edge frags) use line-per-instr k-map
//   [49152, 65536)   W2F bf16 frag-order, sigma (h physical-k permutation) baked in
//   [65536, 66048)   g1 f32 [128] = b1 + global_attr @ W1[192:256]
//   [66560, ...)     node_bf16 [N][64]
#define WS_NODEBF_OFF 66560

__global__ void prep_kernel(const float* __restrict__ W1, const float* __restrict__ b1,
                            const float* __restrict__ W2, const float* __restrict__ gattr,
                            __bf16* __restrict__ W1F, __bf16* __restrict__ W2F,
                            float* __restrict__ g1) {
    int tid = blockIdx.x * blockDim.x + threadIdx.x;
    if (tid < 128 * 192) {
        int n = tid / 192, k = tid % 192;
        int w = n >> 5, nt2 = (n >> 4) & 1, c = n & 15;
        int f = k >> 5, r = k & 31;
        int g, j;
        if (f < 2) {  // edge frags: lane (g,j) holds klog = f*32 + (j>>2)*16 + g*4 + (j&3)
            g = (r >> 2) & 3;
            j = ((r >> 4) & 1) * 4 + (r & 3);
        } else {      // node frags: klog = f*32 + g*8 + j
            g = (r >> 3) & 3;
            j = r & 7;
        }
        W1F[((((w * 2 + nt2) * 6 + f) * 64) + c + 16 * g) * 8 + j] = (__bf16)W1[k * 128 + n];
    } else if (tid < 128 * 192 + 64 * 128) {
        int t = tid - 128 * 192;
        int n = t / 128, p = t % 128;   // p = PHYSICAL k slot (h_frag column)
        int w = n >> 4, c = n & 15;
        int ks = p >> 5, g = (p >> 3) & 3, j = p & 7;
        // sigma: physical p = w1*32 + 2*cc + half  <->  klog = w1*32 + half*16 + cc
        int klog = (p >> 5) * 32 + (p & 1) * 16 + ((p >> 1) & 15);
        W2F[(((w * 4 + ks) * 64) + c + 16 * g) * 8 + j] = (__bf16)W2[klog * 64 + n];
    } else if (tid < 128 * 192 + 64 * 128 + 128) {
        int n = tid - (128 * 192 + 64 * 128);
        float acc = b1[n];
        for (int j = 0; j < 64; ++j) acc += gattr[j] * W1[(192 + j) * 128 + n];
        g1[n] = acc;
    }
}

__global__ __launch_bounds__(256) void node_conv_kernel(const float* __restrict__ nf,
                                                        __bf16* __restrict__ nb, int n8) {
    int t = blockIdx.x * blockDim.x + threadIdx.x;
    if (t < n8) {
        f32x4 a = *(const f32x4*)(nf + (long)t * 8);
        f32x4 b = *(const f32x4*)(nf + (long)t * 8 + 4);
        bf16x8 o;
#pragma unroll
        for (int j = 0; j < 4; ++j) { o[j] = (__bf16)a[j]; o[4 + j] = (__bf16)b[j]; }
        *(bf16x8*)(nb + (long)t * 8) = o;
    }
}

__device__ __forceinline__ f32x4 mk4(float v) {
    f32x4 r; r[0] = v; r[1] = v; r[2] = v; r[3] = v; return r;
}

__device__ __forceinline__ bf16x8 cvt8(f32x4 lo, f32x4 hi) {
    bf16x8 t;
#pragma unroll
    for (int j = 0; j < 4; ++j) { t[j] = (__bf16)lo[j]; t[4 + j] = (__bf16)hi[j]; }
    return t;
}

__global__ __launch_bounds__(128, 2) void edge_mlp_kernel(
    const float* __restrict__ edge_feats, const __bf16* __restrict__ node_bf,
    const int* __restrict__ senders, const int* __restrict__ receivers,
    const __bf16* __restrict__ W1F, const __bf16* __restrict__ W2F,
    const float* __restrict__ g1, const float* __restrict__ b2,
    float* __restrict__ out, int E, int numTiles)
{
    __shared__ __bf16 hb[2][2048];   // double-buffered frag-order h, 4KB each

    const int lane = threadIdx.x & 63;
    const int v    = threadIdx.x >> 6;    // wave 0/1
    const int c    = lane & 15;
    const int g    = lane >> 4;
    const int G    = gridDim.x;

    // ---- pinned weights (per-wave half) ----
    bf16x8 wb1[4][6];
#pragma unroll
    for (int nt = 0; nt < 4; ++nt)
#pragma unroll
        for (int f = 0; f < 6; ++f)
            wb1[nt][f] = *(const bf16x8*)(W1F + (((v * 4 + nt) * 6 + f) * 64 + lane) * 8);
    bf16x8 wb2[2][4];
#pragma unroll
    for (int o = 0; o < 2; ++o)
#pragma unroll
        for (int ks = 0; ks < 4; ++ks)
            wb2[o][ks] = *(const bf16x8*)(W2F + (((v * 2 + o) * 4 + ks) * 64 + lane) * 8);
    float g1v[4];
#pragma unroll
    for (int nt = 0; nt < 4; ++nt) g1v[nt] = g1[v * 64 + nt * 16 + c];
    float b2v[2];
#pragma unroll
    for (int o = 0; o < 2; ++o) b2v[o] = b2[(v * 2 + o) * 16 + c];
    const int sr = SWZ(c * 4 + g);

    // ---- prologue: gather tile blockIdx.x; idx for tile +G ----
    f32x4 se0, se1, se2, se3;
    bf16x8 sn0, sn1, sn2, sn3;
    int iRa, iSa;
    {
        long rc = (long)blockIdx.x * 16 + c;
        if (rc > (long)E - 1) rc = (long)E - 1;
        int iR = receivers[rc], iS = senders[rc];
        const __bf16* pr = node_bf + ((long)iR << 6) + g * 8;
        const __bf16* ps = node_bf + ((long)iS << 6) + g * 8;
        sn0 = *(const bf16x8*)(pr);
        sn1 = *(const bf16x8*)(pr + 32);
        sn2 = *(const bf16x8*)(ps);
        sn3 = *(const bf16x8*)(ps + 32);
        const float* pe = edge_feats + (rc << 6) + g * 4;   // line-per-instr layout
        se0 = *(const f32x4*)(pe);
        se1 = *(const f32x4*)(pe + 16);
        se2 = *(const f32x4*)(pe + 32);
        se3 = *(const f32x4*)(pe + 48);
        long r1 = ((long)blockIdx.x + G) * 16 + c;
        if (r1 > (long)E - 1) r1 = (long)E - 1;
        iRa = receivers[r1]; iSa = senders[r1];
    }

    int buf = 0;
    for (int t = blockIdx.x; t < numTiles; t += G) {
        // consume stage into MFMA frags (A stays in registers)
        bf16x8 a0 = cvt8(se0, se1);
        bf16x8 a1 = cvt8(se2, se3);
        bf16x8 a2 = sn0, a3 = sn1, a4 = sn2, a5 = sn3;

        // T14: issue next tile's gathers; idx 2 tiles ahead
        if (t + G < numTiles) {
            const __bf16* pr = node_bf + ((long)iRa << 6) + g * 8;
            const __bf16* ps = node_bf + ((long)iSa << 6) + g * 8;
            sn0 = *(const bf16x8*)(pr);
            sn1 = *(const bf16x8*)(pr + 32);
            sn2 = *(const bf16x8*)(ps);
            sn3 = *(const bf16x8*)(ps + 32);
            long rn = ((long)t + G) * 16 + c;
            if (rn > (long)E - 1) rn = (long)E - 1;
            const float* pe = edge_feats + (rn << 6) + g * 4;
            se0 = *(const f32x4*)(pe);
            se1 = *(const f32x4*)(pe + 16);
            se2 = *(const f32x4*)(pe + 32);
            se3 = *(const f32x4*)(pe + 48);
            long r2 = ((long)t + 2L * G) * 16 + c;
            if (r2 > (long)E - 1) r2 = (long)E - 1;
            iRa = receivers[r2]; iSa = senders[r2];
        }
        __builtin_amdgcn_sched_barrier(0);

        // ---- GEMM1: 16 edges x 64 hidden cols (this wave's half), 24 MFMA, no LDS ----
        f32x4 acc[4];
#pragma unroll
        for (int nt = 0; nt < 4; ++nt) acc[nt] = mk4(g1v[nt]);
#pragma unroll
        for (int nt = 0; nt < 4; ++nt) {
            acc[nt] = __builtin_amdgcn_mfma_f32_16x16x32_bf16(a0, wb1[nt][0], acc[nt], 0, 0, 0);
            acc[nt] = __builtin_amdgcn_mfma_f32_16x16x32_bf16(a1, wb1[nt][1], acc[nt], 0, 0, 0);
            acc[nt] = __builtin_amdgcn_mfma_f32_16x16x32_bf16(a2, wb1[nt][2], acc[nt], 0, 0, 0);
            acc[nt] = __builtin_amdgcn_mfma_f32_16x16x32_bf16(a3, wb1[nt][3], acc[nt], 0, 0, 0);
            acc[nt] = __builtin_amdgcn_mfma_f32_16x16x32_bf16(a4, wb1[nt][4], acc[nt], 0, 0, 0);
            acc[nt] = __builtin_amdgcn_mfma_f32_16x16x32_bf16(a5, wb1[nt][5], acc[nt], 0, 0, 0);
        }

        // ---- relu -> swizzled frag-order h (regions = k-blocks v*2+np2) ----
#pragma unroll
        for (int np2 = 0; np2 < 2; ++np2)
#pragma unroll
            for (int r = 0; r < 4; ++r) {
                float v0 = acc[np2 * 2][r];     v0 = v0 > 0.f ? v0 : 0.f;
                float v1 = acc[np2 * 2 + 1][r]; v1 = v1 > 0.f ? v1 : 0.f;
                bf16x2 pk; pk[0] = (__bf16)v0; pk[1] = (__bf16)v1;
                int s = SWZ(g * 16 + r * 4 + (c >> 2));
                *(bf16x2*)&hb[buf][(v * 2 + np2) * 512 + s * 8 + ((c & 3) << 1)] = pk;
            }

        // the ONE barrier: h visible to the partner wave
        asm volatile("s_waitcnt lgkmcnt(0)" ::: "memory");
        __builtin_amdgcn_s_barrier();

        // ---- GEMM2: 16 edges x 32 out cols (this wave's half), 4 ds_read + 8 MFMA ----
        f32x4 acc2[2];
#pragma unroll
        for (int o = 0; o < 2; ++o) acc2[o] = mk4(b2v[o]);
#pragma unroll
        for (int ks = 0; ks < 4; ++ks) {
            bf16x8 ah = *(const bf16x8*)&hb[buf][ks * 512 + sr * 8];
            acc2[0] = __builtin_amdgcn_mfma_f32_16x16x32_bf16(ah, wb2[0][ks], acc2[0], 0, 0, 0);
            acc2[1] = __builtin_amdgcn_mfma_f32_16x16x32_bf16(ah, wb2[1][ks], acc2[1], 0, 0, 0);
        }

        // ---- stores: full-line 64B segments ----
#pragma unroll
        for (int o = 0; o < 2; ++o)
#pragma unroll
            for (int r = 0; r < 4; ++r) {
                long orow = (long)t * 16 + g * 4 + r;
                if (orow < E) out[orow * 64 + (v * 2 + o) * 16 + c] = acc2[o][r];
            }

        buf ^= 1;  // dbuf: next h-writes go to the other buffer; WAR ordered by the barrier
    }
}

// fallback (ws too small for node table): r8 structure, f32 gathers, permuted edge loads
__global__ __launch_bounds__(256) void edge_mlp_fallback(
    const float* __restrict__ edge_feats, const float* __restrict__ node_feats,
    const int* __restrict__ senders, const int* __restrict__ receivers,
    const __bf16* __restrict__ W1F, const __bf16* __restrict__ W2F,
    const float* __restrict__ g1, const float* __restrict__ b2,
    float* __restrict__ out, int E, int numTiles)
{
    __shared__ __bf16 A_lds[4 * 6 * 64 * 8];
    __shared__ __bf16 h_frag[4 * 4 * 64 * 8];
    const int lane = threadIdx.x & 63;
    const int w = threadIdx.x >> 6;
    const int c = lane & 15;
    const int g = lane >> 4;
    const int G = gridDim.x;

    bf16x8 wb1[2][6];
#pragma unroll
    for (int nt2 = 0; nt2 < 2; ++nt2)
#pragma unroll
        for (int f = 0; f < 6; ++f)
            wb1[nt2][f] = *(const bf16x8*)(W1F + (((w * 2 + nt2) * 6 + f) * 64 + lane) * 8);
    bf16x8 wb2[4];
#pragma unroll
    for (int ks = 0; ks < 4; ++ks)
        wb2[ks] = *(const bf16x8*)(W2F + ((w * 4 + ks) * 64 + lane) * 8);
    const float g1v0 = g1[w * 32 + c];
    const float g1v1 = g1[w * 32 + 16 + c];
    const float b2v  = b2[w * 16 + c];
    const int sr = SWZ(c * 4 + g);

    for (int t = blockIdx.x; t < numTiles; t += G) {
        long rowc = (long)t * 64 + w * 16 + c;
        if (rowc > (long)E - 1) rowc = (long)E - 1;
        int iR = receivers[rowc], iS = senders[rowc];
        const float* pr = node_feats + ((long)iR << 6) + g * 8;
        const float* ps = node_feats + ((long)iS << 6) + g * 8;
        const float* pe = edge_feats + (rowc << 6) + g * 4;   // permuted layout
        f32x4 e0a = *(const f32x4*)(pe),      e0b = *(const f32x4*)(pe + 16);
        f32x4 e1a = *(const f32x4*)(pe + 32), e1b = *(const f32x4*)(pe + 48);
        f32x4 r0a = *(const f32x4*)(pr),      r0b = *(const f32x4*)(pr + 4);
        f32x4 r1a = *(const f32x4*)(pr + 32), r1b = *(const f32x4*)(pr + 36);
        f32x4 s0a = *(const f32x4*)(ps),      s0b = *(const f32x4*)(ps + 4);
        f32x4 s1a = *(const f32x4*)(ps + 32), s1b = *(const f32x4*)(ps + 36);

        __bf16* ab = A_lds + w * 6 * 512 + lane * 8;
        *(bf16x8*)(ab)        = cvt8(e0a, e0b);
        *(bf16x8*)(ab + 512)  = cvt8(e1a, e1b);
        *(bf16x8*)(ab + 1024) = cvt8(r0a, r0b);
        *(bf16x8*)(ab + 1536) = cvt8(r1a, r1b);
        *(bf16x8*)(ab + 2048) = cvt8(s0a, s0b);
        *(bf16x8*)(ab + 2560) = cvt8(s1a, s1b);
        __syncthreads();

        f32x4 acc0[4], acc1[4];
#pragma unroll
        for (int mt = 0; mt < 4; ++mt) { acc0[mt] = mk4(g1v0); acc1[mt] = mk4(g1v1); }
#pragma unroll
        for (int mt = 0; mt < 4; ++mt)
#pragma unroll
            for (int f = 0; f < 6; ++f) {
                bf16x8 a = *(const bf16x8*)(A_lds + ((mt * 6 + f) * 64 + lane) * 8);
                acc0[mt] = __builtin_amdgcn_mfma_f32_16x16x32_bf16(a, wb1[0][f], acc0[mt], 0, 0, 0);
                acc1[mt] = __builtin_amdgcn_mfma_f32_16x16x32_bf16(a, wb1[1][f], acc1[mt], 0, 0, 0);
            }
#pragma unroll
        for (int mt = 0; mt < 4; ++mt)
#pragma unroll
            for (int r = 0; r < 4; ++r) {
                float v0 = acc0[mt][r]; v0 = v0 > 0.f ? v0 : 0.f;
                float v1 = acc1[mt][r]; v1 = v1 > 0.f ? v1 : 0.f;
                bf16x2 pk; pk[0] = (__bf16)v0; pk[1] = (__bf16)v1;
                int s = SWZ(g * 16 + r * 4 + (c >> 2));
                *(bf16x2*)&h_frag[((mt * 4 + w) * 512) + s * 8 + ((c & 3) << 1)] = pk;
            }
        __syncthreads();

        f32x4 acc2[4];
#pragma unroll
        for (int mt = 0; mt < 4; ++mt) acc2[mt] = mk4(b2v);
#pragma unroll
        for (int mt = 0; mt < 4; ++mt)
#pragma unroll
            for (int ks = 0; ks < 4; ++ks) {
                bf16x8 ah = *(const bf16x8*)&h_frag[(mt * 4 + ks) * 512 + sr * 8];
                acc2[mt] = __builtin_amdgcn_mfma_f32_16x16x32_bf16(ah, wb2[ks], acc2[mt], 0, 0, 0);
            }
#pragma unroll
        for (int mt = 0; mt < 4; ++mt)
#pragma unroll
            for (int r = 0; r < 4; ++r) {
                long orow = (long)t * 64 + mt * 16 + g * 4 + r;
                if (orow < E) out[orow * 64 + w * 16 + c] = acc2[mt][r];
            }
        __syncthreads();
    }
}

extern "C" void kernel_launch(void* const* d_in, const int* in_sizes, int n_in,
                              void* d_out, int out_size, void* d_ws, size_t ws_size,
                              hipStream_t stream) {
    const float* edge_feats = (const float*)d_in[0];
    const float* node_feats = (const float*)d_in[1];
    const float* gattr      = (const float*)d_in[2];
    const int*   senders    = (const int*)d_in[3];
    const int*   receivers  = (const int*)d_in[4];
    const float* W1         = (const float*)d_in[5];
    const float* b1         = (const float*)d_in[6];
    const float* W2         = (const float*)d_in[7];
    const float* b2         = (const float*)d_in[8];
    float* out = (float*)d_out;

    const int E = in_sizes[3];        // N_EDGES
    const int N = in_sizes[1] / 64;   // N_NODES

    char* ws = (char*)d_ws;
    __bf16* W1F = (__bf16*)ws;
    __bf16* W2F = (__bf16*)(ws + 49152);
    float*  g1  = (float*)(ws + 49152 + 16384);
    __bf16* nodeBF = (__bf16*)(ws + WS_NODEBF_OFF);

    const size_t ws_needed = (size_t)WS_NODEBF_OFF + (size_t)N * 64 * 2;
    const bool useNB = ws_size >= ws_needed;

    int prep_total = 128 * 192 + 64 * 128 + 128;
    prep_kernel<<<(prep_total + 255) / 256, 256, 0, stream>>>(W1, b1, W2, gattr, W1F, W2F, g1);

    if (useNB) {
        int n8 = N * 8;
        node_conv_kernel<<<(n8 + 255) / 256, 256, 0, stream>>>(node_feats, nodeBF, n8);
        const int numTiles16 = (E + 15) / 16;
        int grid = numTiles16 < GRID_MAIN ? numTiles16 : GRID_MAIN;
        edge_mlp_kernel<<<grid, 128, 0, stream>>>(edge_feats, nodeBF, senders, receivers,
                                                  W1F, W2F, g1, b2, out, E, numTiles16);
    } else {
        const int numTiles64 = (E + 63) / 64;
        int grid = numTiles64 < 2048 ? numTiles64 : 2048;
        edge_mlp_fallback<<<grid, 256, 0, stream>>>(edge_feats, node_feats, senders, receivers,
                                                    W1F, W2F, g1, b2, out, E, numTiles64);
    }
}